// Round 1
// baseline (423.079 us; speedup 1.0000x reference)
//
#include <hip/hip_runtime.h>
#include <hip/hip_bf16.h>

// ---------------------------------------------------------------------------
// GraphSAGE 3-layer encoder, fp32 in/out.
//   per layer: h_out = relu?( mean_agg(h)@Wl + b + h@Wr )
// Identity: segment_sum(h[src])@Wl == segment_sum((h@Wl)[src])
//   -> project first (MFMA bf16), aggregate small vectors via CSR gather.
// R7 -> R8:
//   * proj was latency/occupancy-bound: 25% HBM BW, MfmaUtil 3.6%, VALUBusy
//     12%, Occupancy 33.5% (16 waves/CU cap from __launch_bounds__(256,4)).
//     Traffic itself was ideal (no over-fetch, 0 bank conflicts) -> the fix
//     is TLP, not access patterns.
//   * proj blocks now 512 threads (8 waves), __launch_bounds__(BT,8):
//     4 blocks/CU x 8 waves = 32 waves/CU (proj1 LDS 32KB x4 = 128KB <= 160),
//     VGPR cap unchanged at 64 so per-wave codegen is identical.
//   * proj1: CH=2 -> NG=4, npi=64, grid 1024 (~3 grid-stride iters/block).
//     proj2/proj3: CH=1, NU=2, npi=256, grid 782 (one trip, ~24 waves/CU
//     resident vs ~12 before).
// ---------------------------------------------------------------------------

typedef __attribute__((ext_vector_type(8))) short short8;
typedef __attribute__((ext_vector_type(4))) float f32x4;

__device__ inline unsigned short f2b(float x) {
    return __bfloat16_as_ushort(__float2bfloat16(x));
}
__device__ inline float b2f(unsigned short u) {
    return __uint_as_float(((unsigned)u) << 16);
}

// ============================ CSR construction =============================

__global__ void zero_ints(int* __restrict__ p, int n) {
    int i = blockIdx.x * blockDim.x + threadIdx.x;
    if (i < n) p[i] = 0;
}

__global__ void hist_kernel(const int* __restrict__ dst, int* __restrict__ deg, int E) {
    int i = blockIdx.x * blockDim.x + threadIdx.x;
    if (i < E) atomicAdd(&deg[dst[i]], 1);
}

__global__ void scan_reduce(const int* __restrict__ deg, int* __restrict__ bsum, int n) {
    __shared__ int s[256];
    int i = blockIdx.x * 256 + threadIdx.x;
    s[threadIdx.x] = (i < n) ? deg[i] : 0;
    __syncthreads();
    for (int off = 128; off > 0; off >>= 1) {
        if (threadIdx.x < off) s[threadIdx.x] += s[threadIdx.x + off];
        __syncthreads();
    }
    if (threadIdx.x == 0) bsum[blockIdx.x] = s[0];
}

__global__ void scan_top(int* __restrict__ bsum, int nb) {
    __shared__ int s[1024];
    int t = threadIdx.x;
    int v = (t < nb) ? bsum[t] : 0;
    s[t] = v;
    __syncthreads();
    for (int off = 1; off < 1024; off <<= 1) {
        int add = (t >= off) ? s[t - off] : 0;
        __syncthreads();
        s[t] += add;
        __syncthreads();
    }
    if (t < nb) bsum[t] = s[t] - v;  // exclusive
}

__global__ void scan_final(const int* __restrict__ deg, const int* __restrict__ bsum,
                           int* __restrict__ rowptr, int* __restrict__ cursor,
                           int n, int E) {
    __shared__ int s[256];
    int t = threadIdx.x;
    int i = blockIdx.x * 256 + t;
    int v = (i < n) ? deg[i] : 0;
    s[t] = v;
    __syncthreads();
    for (int off = 1; off < 256; off <<= 1) {
        int add = (t >= off) ? s[t - off] : 0;
        __syncthreads();
        s[t] += add;
        __syncthreads();
    }
    int excl = s[t] - v + bsum[blockIdx.x];
    if (i < n) {
        rowptr[i] = excl;
        cursor[i] = excl;
    }
    if (i == 0) rowptr[n] = E;
}

__global__ void fill_kernel(const int* __restrict__ src, const int* __restrict__ dst,
                            int* __restrict__ cursor, int* __restrict__ csr, int E) {
    int e = blockIdx.x * blockDim.x + threadIdx.x;
    if (e < E) {
        int pos = atomicAdd(&cursor[dst[e]], 1);
        csr[pos] = src[e];
    }
}

// ============================ MFMA projection ==============================
// p = x@Wl ; r = x@Wr + b in one pass. Weight cols concatenated:
// [0,DP)->p, [DP,DP+DR)->r, rest zero-pad.
// LDS holds B fragments in FRAGMENT ORDER: chunk ((t*S+s)*64+lane) holds
// W~[k0..k0+7][c] for c = t*16+(lane&15), k0 = s*32+(lane>>4)*8 -> a wave's
// ds_read_b128 is lane-contiguous (conflict-free 8-phase floor).
// Raw x double-buffered in registers across grid-stride iterations; cvt/relu
// deferred to compute phase.
// MFMA 16x16x32: A[m=lane&15][k=(lane>>4)*8+i]; D col=lane&15,
// row=(lane>>4)*4+reg (verified R3-R6).

template <int BT, int DIN, int DP, int DR, int DT2, int CH, int NU,
          bool RELU, bool IN_BF16, bool OUT_BF16>
__launch_bounds__(BT, 8)
__global__ void proj_mfma(const void* __restrict__ xv,
                          const float* __restrict__ Wl,
                          const float* __restrict__ Wr,
                          const float* __restrict__ bl,
                          void* __restrict__ pv,
                          void* __restrict__ rv,
                          int n) {
    constexpr int WAVES = BT / 64;
    constexpr int NG = WAVES / CH;       // wave node-slots per block
    constexpr int TILES = DT2 / 16;
    constexpr int TW = TILES / CH;       // col tiles per wave
    constexpr int S = DIN / 32;          // MFMA k-steps
    constexpr int NCH = TILES * S * 64;  // 16B fragment chunks

    __shared__ unsigned short sF[NCH * 8];

    const int tid = threadIdx.x;
    // stage weights as lane-ordered fragments (8 scalar col-gather loads each)
    for (int chunk = tid; chunk < NCH; chunk += BT) {
        const int lane_c = chunk & 63;
        const int rest = chunk >> 6;         // t*S + s
        const int s = rest % S;
        const int t = rest / S;
        const int c = t * 16 + (lane_c & 15);
        const int k0 = s * 32 + (lane_c >> 4) * 8;
        short8 pack;
#pragma unroll
        for (int j = 0; j < 8; ++j) {
            float w = 0.f;
            const int k = k0 + j;
            if (c < DP) w = Wl[k * DP + c];
            else if (c < DP + DR) w = Wr[k * DR + (c - DP)];
            pack[j] = (short)f2b(w);
        }
        *reinterpret_cast<short8*>(&sF[(size_t)chunk * 8]) = pack;
    }
    __syncthreads();

    const int wave = tid >> 6, lane = tid & 63;
    const int ng = wave % NG;
    const int ch = wave / NG;
    const int q = lane >> 4, ln = lane & 15;
    const int colbase = ch * (TW * 16);

    // lane's fragment base: frag (t,s) at +(t*S+s)*512 ushorts
    const unsigned short* fbase = &sF[((size_t)(ch * TW * S) * 64 + lane) * 8];

    int colg[TW];
    float bias[TW];
#pragma unroll
    for (int t = 0; t < TW; ++t) {
        colg[t] = colbase + t * 16 + ln;
        bias[t] = (colg[t] >= DP && colg[t] < DP + DR) ? bl[colg[t] - DP] : 0.0f;
    }

    // raw-x double buffers (unused dtype pair is DCE'd)
    float4 rf0[NU][2 * S], rf1[NU][2 * S];
    short8 rb0[NU][S], rb1[NU][S];

    auto load_groups = [&](float4 (&rf)[NU][2 * S], short8 (&rb)[NU][S], int nbase) {
#pragma unroll
        for (int g = 0; g < NU; ++g) {
            const int base = nbase + (ng * NU + g) * 16;
            if (base >= n) continue;  // wave-uniform
            if constexpr (IN_BF16) {
                const unsigned short* xr =
                    (const unsigned short*)xv + (size_t)(base + ln) * DIN + q * 8;
#pragma unroll
                for (int s = 0; s < S; ++s)
                    rb[g][s] = *reinterpret_cast<const short8*>(xr + s * 32);
            } else {
                const float* xr = (const float*)xv + (size_t)(base + ln) * DIN + q * 8;
#pragma unroll
                for (int s = 0; s < S; ++s) {
                    rf[g][2 * s]     = *reinterpret_cast<const float4*>(xr + s * 32);
                    rf[g][2 * s + 1] = *reinterpret_cast<const float4*>(xr + s * 32 + 4);
                }
            }
        }
    };

    auto compute_groups = [&](float4 (&rf)[NU][2 * S], short8 (&rb)[NU][S], int nbase) {
#pragma unroll
        for (int g = 0; g < NU; ++g) {
            const int base = nbase + (ng * NU + g) * 16;
            if (base >= n) continue;
            short8 af[S];
#pragma unroll
            for (int s = 0; s < S; ++s) {
                if constexpr (IN_BF16) {
                    short8 a = rb[g][s];
                    if (RELU) {
#pragma unroll
                        for (int j = 0; j < 8; ++j)
                            a[j] = ((short)a[j] < 0) ? (short)0 : a[j];
                    }
                    af[s] = a;
                } else {
                    float4 v0 = rf[g][2 * s], v1 = rf[g][2 * s + 1];
                    if (RELU) {
                        v0.x = fmaxf(v0.x, 0.0f); v0.y = fmaxf(v0.y, 0.0f);
                        v0.z = fmaxf(v0.z, 0.0f); v0.w = fmaxf(v0.w, 0.0f);
                        v1.x = fmaxf(v1.x, 0.0f); v1.y = fmaxf(v1.y, 0.0f);
                        v1.z = fmaxf(v1.z, 0.0f); v1.w = fmaxf(v1.w, 0.0f);
                    }
                    short8 a;
                    a[0] = (short)f2b(v0.x); a[1] = (short)f2b(v0.y);
                    a[2] = (short)f2b(v0.z); a[3] = (short)f2b(v0.w);
                    a[4] = (short)f2b(v1.x); a[5] = (short)f2b(v1.y);
                    a[6] = (short)f2b(v1.z); a[7] = (short)f2b(v1.w);
                    af[s] = a;
                }
            }

            f32x4 acc[TW];
#pragma unroll
            for (int t = 0; t < TW; ++t) acc[t] = (f32x4){0.f, 0.f, 0.f, 0.f};
#pragma unroll
            for (int s = 0; s < S; ++s)
#pragma unroll
                for (int t = 0; t < TW; ++t) {
                    short8 bf = *reinterpret_cast<const short8*>(
                        fbase + (size_t)(t * S + s) * 512);
                    acc[t] = __builtin_amdgcn_mfma_f32_16x16x32_bf16(
                        af[s], bf, acc[t], 0, 0, 0);
                }

#pragma unroll
            for (int t = 0; t < TW; ++t) {
                const int c = colg[t];
#pragma unroll
                for (int rr = 0; rr < 4; ++rr) {
                    const int row = base + q * 4 + rr;
                    if (c < DP) {
                        if constexpr (OUT_BF16)
                            ((unsigned short*)pv)[(size_t)row * DP + c] = f2b(acc[t][rr]);
                        else
                            ((float*)pv)[(size_t)row * DP + c] = acc[t][rr];
                    } else if (c < DP + DR) {
                        const float v = acc[t][rr] + bias[t];
                        if constexpr (OUT_BF16)
                            ((unsigned short*)rv)[(size_t)row * DR + (c - DP)] = f2b(v);
                        else
                            ((float*)rv)[(size_t)row * DR + (c - DP)] = v;
                    }
                }
            }
        }
    };

    const int npi = NG * NU * 16;        // nodes per block-iteration
    const int stride = gridDim.x * npi;
    int nb = blockIdx.x * npi;
    if (nb >= n) return;
    load_groups(rf0, rb0, nb);
    while (true) {
        const int nb1 = nb + stride;
        if (nb1 < n) load_groups(rf1, rb1, nb1);
        compute_groups(rf0, rb0, nb);
        nb = nb1;
        if (nb >= n) break;
        const int nb2 = nb + stride;
        if (nb2 < n) load_groups(rf0, rb0, nb2);
        compute_groups(rf1, rb1, nb);
        nb = nb2;
        if (nb >= n) break;
    }
}

// ============================ aggregation ==================================
// out[d] += mean over csr row of p rows. bf16 buffers: L=D/8 lanes per node,
// one short8 per lane per gathered row; fp32 accumulation; unroll-4 keeps
// 4 independent csr->row chains in flight.

template <int D, int L>
__global__ void agg_bf16(const int* __restrict__ rowptr,
                         const int* __restrict__ csr,
                         const unsigned short* __restrict__ p,
                         unsigned short* __restrict__ out,
                         int n) {
    constexpr int RQ = D / 8;            // short8s per row
    long long gid = (long long)blockIdx.x * blockDim.x + threadIdx.x;
    int d = (int)(gid / L);
    int l = (int)(gid % L);
    if (d >= n) return;
    int beg = rowptr[d], end = rowptr[d + 1];
    int deg = end - beg;
    if (deg <= 0) return;

    const short8* pr = reinterpret_cast<const short8*>(p);
    float s[8];
#pragma unroll
    for (int j = 0; j < 8; ++j) s[j] = 0.0f;

    int i = beg;
    for (; i + 4 <= end; i += 4) {
        int e0 = csr[i], e1 = csr[i + 1], e2 = csr[i + 2], e3 = csr[i + 3];
        short8 a = pr[(size_t)e0 * RQ + l];
        short8 b = pr[(size_t)e1 * RQ + l];
        short8 c = pr[(size_t)e2 * RQ + l];
        short8 e = pr[(size_t)e3 * RQ + l];
#pragma unroll
        for (int j = 0; j < 8; ++j)
            s[j] += (b2f((unsigned short)a[j]) + b2f((unsigned short)b[j])) +
                    (b2f((unsigned short)c[j]) + b2f((unsigned short)e[j]));
    }
    for (; i < end; ++i) {
        short8 a = pr[(size_t)csr[i] * RQ + l];
#pragma unroll
        for (int j = 0; j < 8; ++j) s[j] += b2f((unsigned short)a[j]);
    }

    const float inv = 1.0f / (float)deg;
    short8* o = reinterpret_cast<short8*>(out) + (size_t)d * RQ + l;
    short8 cur = *o;
#pragma unroll
    for (int j = 0; j < 8; ++j) {
        float v = b2f((unsigned short)cur[j]) + s[j] * inv;
        cur[j] = (short)f2b(v);
    }
    *o = cur;
}

// fp32 variant for the final layer (out = d_out, fp32)
template <int D, int L>
__global__ void agg_f32(const int* __restrict__ rowptr,
                        const int* __restrict__ csr,
                        const float* __restrict__ p,
                        float* __restrict__ out,
                        int n) {
    constexpr int RQ = D / 4;            // float4s per row
    long long gid = (long long)blockIdx.x * blockDim.x + threadIdx.x;
    int d = (int)(gid / L);
    int l = (int)(gid % L);
    if (d >= n || l >= RQ) return;
    int beg = rowptr[d], end = rowptr[d + 1];
    int deg = end - beg;
    if (deg <= 0) return;

    const float4* pr = reinterpret_cast<const float4*>(p);
    float sx = 0.f, sy = 0.f, sz = 0.f, sw = 0.f;
    int i = beg;
    for (; i + 4 <= end; i += 4) {
        int s0 = csr[i], s1 = csr[i + 1], s2 = csr[i + 2], s3 = csr[i + 3];
        float4 a = pr[(size_t)s0 * RQ + l];
        float4 b = pr[(size_t)s1 * RQ + l];
        float4 c = pr[(size_t)s2 * RQ + l];
        float4 e = pr[(size_t)s3 * RQ + l];
        sx += (a.x + b.x) + (c.x + e.x);
        sy += (a.y + b.y) + (c.y + e.y);
        sz += (a.z + b.z) + (c.z + e.z);
        sw += (a.w + b.w) + (c.w + e.w);
    }
    for (; i < end; ++i) {
        float4 a = pr[(size_t)csr[i] * RQ + l];
        sx += a.x; sy += a.y; sz += a.z; sw += a.w;
    }
    const float inv = 1.0f / (float)deg;
    float4* o = reinterpret_cast<float4*>(out) + (size_t)d * RQ + l;
    float4 cur = *o;
    cur.x += sx * inv; cur.y += sy * inv;
    cur.z += sz * inv; cur.w += sw * inv;
    *o = cur;
}

// ============================ launcher =====================================

extern "C" void kernel_launch(void* const* d_in, const int* in_sizes, int n_in,
                              void* d_out, int out_size, void* d_ws, size_t ws_size,
                              hipStream_t stream) {
    const float* x   = (const float*)d_in[0];
    const int*   ei  = (const int*)d_in[1];   // (2, E) int32
    const float* Wl1 = (const float*)d_in[2];
    const float* bl1 = (const float*)d_in[3];
    const float* Wr1 = (const float*)d_in[4];
    const float* Wl2 = (const float*)d_in[5];
    const float* bl2 = (const float*)d_in[6];
    const float* Wr2 = (const float*)d_in[7];
    const float* Wl3 = (const float*)d_in[8];
    const float* bl3 = (const float*)d_in[9];
    const float* Wr3 = (const float*)d_in[10];
    float* out = (float*)d_out;

    const int N = in_sizes[0] / 128;
    const int E = in_sizes[1] / 2;
    const int* src  = ei;
    const int* dstp = ei + E;

    // workspace (bf16 intermediates):
    //   A1 bf16 N*64 | B bf16 N*64 | A2 bf16 N*32 | C bf16 N*32 |
    //   A3 f32 N*20 | rowptr (N+1) | csr (E)
    // transient CSR ints (degi, cursor, bsum) alias A3 (dead before proj3).
    unsigned short* A1 = (unsigned short*)d_ws;
    unsigned short* Bb = A1 + (size_t)N * 64;
    unsigned short* A2 = Bb + (size_t)N * 64;
    unsigned short* Cb = A2 + (size_t)N * 32;
    float* A3 = (float*)(Cb + (size_t)N * 32);
    int* rowptr = (int*)(A3 + (size_t)N * 20);
    int* csr    = rowptr + (N + 1);

    int* degi   = (int*)A3;
    int* cursor = degi + N;
    int* bsum   = cursor + N;

    const int NB = (N + 255) / 256;  // 782 <= 1024 (scan_top limit)

    // --- CSR build ---
    zero_ints<<<NB, 256, 0, stream>>>(degi, N);
    hist_kernel<<<(E + 255) / 256, 256, 0, stream>>>(dstp, degi, E);
    scan_reduce<<<NB, 256, 0, stream>>>(degi, bsum, N);
    scan_top<<<1, 1024, 0, stream>>>(bsum, NB);
    scan_final<<<NB, 256, 0, stream>>>(degi, bsum, rowptr, cursor, N, E);
    fill_kernel<<<(E + 255) / 256, 256, 0, stream>>>(src, dstp, cursor, csr, E);

    // --- layer 1: 128 -> 64 --- fp32 in, bf16 out; 512T/8 waves, CH=2, NU=1
    // npi=64, grid 1024 (4 blocks/CU resident, 32 waves/CU, ~3 iters/block)
    proj_mfma<512, 128, 64, 64, 128, 2, 1, false, false, true><<<1024, 512, 0, stream>>>(
        x, Wl1, Wr1, bl1, A1, Bb, N);
    agg_bf16<64, 8><<<(int)(((long long)N * 8 + 255) / 256), 256, 0, stream>>>(
        rowptr, csr, A1, Bb, N);

    // --- layer 2: 64 -> 32 --- bf16 in (relu), bf16 out; 512T, CH=1, NU=2
    // npi=256, grid 782 (one trip, all resident, ~24 waves/CU)
    proj_mfma<512, 64, 32, 32, 64, 1, 2, true, true, true><<<782, 512, 0, stream>>>(
        Bb, Wl2, Wr2, bl2, A2, Cb, N);
    agg_bf16<32, 4><<<(int)(((long long)N * 4 + 255) / 256), 256, 0, stream>>>(
        rowptr, csr, A2, Cb, N);

    // --- layer 3: 32 -> 20 --- bf16 in (relu), fp32 out (p3=A3, r -> d_out)
    proj_mfma<512, 32, 20, 20, 48, 1, 2, true, true, false><<<782, 512, 0, stream>>>(
        Cb, Wl3, Wr3, bl3, A3, out, N);
    agg_f32<20, 8><<<(int)(((long long)N * 8 + 255) / 256), 256, 0, stream>>>(
        rowptr, csr, A3, out, N);
}

// Round 2
// 344.033 us; speedup vs baseline: 1.2298x; 1.2298x over previous
//
#include <hip/hip_runtime.h>
#include <hip/hip_bf16.h>

// ---------------------------------------------------------------------------
// GraphSAGE 3-layer encoder, fp32 in/out.
//   per layer: h_out = relu?( mean_agg(h)@Wl + b + h@Wr )
// Identity: segment_sum(h[src])@Wl == segment_sum((h@Wl)[src])
//   -> project first (MFMA bf16), aggregate small vectors via CSR gather.
// R8 -> R9:
//   * R8 post-mortem: __launch_bounds__(512,8) capped VGPR at 64 -> allocator
//     gave 32 and SPILLED the fp32 x double-buffers (WRITE_SIZE 54->285 MB).
//     Occupancy theory confirmed though: 64% occ drove 2.0->3.5 TB/s.
//   * R9: raise occupancy via LDS, not the register cap. ch split moved from
//     wave-level to BLOCK-level: each block stages only its 16 KB half of the
//     weight fragments (ch = blockIdx.x % CH). Per-thread codegen identical
//     to R7 (VGPR=64, no spill); 16 KB LDS + 64 VGPR -> 8 blocks/CU =
//     32 waves/CU. Duplicate x reads across ch-block pairs absorbed by L3.
//   * proj2/proj3: NU=4->2 (rb buffers 64->32 regs, target VGPR<=64 for
//     8 blocks/CU), grid 1563 covers N in one trip.
// ---------------------------------------------------------------------------

typedef __attribute__((ext_vector_type(8))) short short8;
typedef __attribute__((ext_vector_type(4))) float f32x4;

__device__ inline unsigned short f2b(float x) {
    return __bfloat16_as_ushort(__float2bfloat16(x));
}
__device__ inline float b2f(unsigned short u) {
    return __uint_as_float(((unsigned)u) << 16);
}

// ============================ CSR construction =============================

__global__ void zero_ints(int* __restrict__ p, int n) {
    int i = blockIdx.x * blockDim.x + threadIdx.x;
    if (i < n) p[i] = 0;
}

__global__ void hist_kernel(const int* __restrict__ dst, int* __restrict__ deg, int E) {
    int i = blockIdx.x * blockDim.x + threadIdx.x;
    if (i < E) atomicAdd(&deg[dst[i]], 1);
}

__global__ void scan_reduce(const int* __restrict__ deg, int* __restrict__ bsum, int n) {
    __shared__ int s[256];
    int i = blockIdx.x * 256 + threadIdx.x;
    s[threadIdx.x] = (i < n) ? deg[i] : 0;
    __syncthreads();
    for (int off = 128; off > 0; off >>= 1) {
        if (threadIdx.x < off) s[threadIdx.x] += s[threadIdx.x + off];
        __syncthreads();
    }
    if (threadIdx.x == 0) bsum[blockIdx.x] = s[0];
}

__global__ void scan_top(int* __restrict__ bsum, int nb) {
    __shared__ int s[1024];
    int t = threadIdx.x;
    int v = (t < nb) ? bsum[t] : 0;
    s[t] = v;
    __syncthreads();
    for (int off = 1; off < 1024; off <<= 1) {
        int add = (t >= off) ? s[t - off] : 0;
        __syncthreads();
        s[t] += add;
        __syncthreads();
    }
    if (t < nb) bsum[t] = s[t] - v;  // exclusive
}

__global__ void scan_final(const int* __restrict__ deg, const int* __restrict__ bsum,
                           int* __restrict__ rowptr, int* __restrict__ cursor,
                           int n, int E) {
    __shared__ int s[256];
    int t = threadIdx.x;
    int i = blockIdx.x * 256 + t;
    int v = (i < n) ? deg[i] : 0;
    s[t] = v;
    __syncthreads();
    for (int off = 1; off < 256; off <<= 1) {
        int add = (t >= off) ? s[t - off] : 0;
        __syncthreads();
        s[t] += add;
        __syncthreads();
    }
    int excl = s[t] - v + bsum[blockIdx.x];
    if (i < n) {
        rowptr[i] = excl;
        cursor[i] = excl;
    }
    if (i == 0) rowptr[n] = E;
}

__global__ void fill_kernel(const int* __restrict__ src, const int* __restrict__ dst,
                            int* __restrict__ cursor, int* __restrict__ csr, int E) {
    int e = blockIdx.x * blockDim.x + threadIdx.x;
    if (e < E) {
        int pos = atomicAdd(&cursor[dst[e]], 1);
        csr[pos] = src[e];
    }
}

// ============================ MFMA projection ==============================
// p = x@Wl ; r = x@Wr + b in one pass. Weight cols concatenated:
// [0,DP)->p, [DP,DP+DR)->r, rest zero-pad.
// Column-tile space split across CH BLOCK classes (ch = blockIdx.x % CH):
// a block stages only its TW = TILES/CH tiles of W fragments -> proj1 LDS
// 16 KB, 8 blocks/CU resident at VGPR=64.
// LDS holds B fragments in FRAGMENT ORDER: chunk ((t*S+s)*64+lane) holds
// W~[k0..k0+7][c] for c = (ch*TW+t)*16+(lane&15), k0 = s*32+(lane>>4)*8 ->
// a wave's ds_read_b128 is lane-contiguous (conflict-free 8-phase floor).
// Raw x double-buffered in registers across grid-stride iterations; cvt/relu
// deferred to compute phase.
// MFMA 16x16x32: A[m=lane&15][k=(lane>>4)*8+i]; D col=lane&15,
// row=(lane>>4)*4+reg (verified R3-R6).

template <int DIN, int DP, int DR, int DT2, int CH, int NU,
          bool RELU, bool IN_BF16, bool OUT_BF16>
__launch_bounds__(256, 4)
__global__ void proj_mfma(const void* __restrict__ xv,
                          const float* __restrict__ Wl,
                          const float* __restrict__ Wr,
                          const float* __restrict__ bl,
                          void* __restrict__ pv,
                          void* __restrict__ rv,
                          int n) {
    constexpr int WAVES = 4;             // 256 threads
    constexpr int TILES = DT2 / 16;
    constexpr int TW = TILES / CH;       // col tiles per block (= per wave)
    constexpr int S = DIN / 32;          // MFMA k-steps
    constexpr int NCH = TW * S * 64;     // 16B fragment chunks staged/block

    __shared__ unsigned short sF[NCH * 8];

    const int ch   = (CH > 1) ? ((int)blockIdx.x % CH) : 0;
    const int blk  = (int)blockIdx.x / CH;
    const int nblk = (int)gridDim.x / CH;

    const int tid = threadIdx.x;
    // stage this block's ch-half of weights as lane-ordered fragments
    for (int chunk = tid; chunk < NCH; chunk += 256) {
        const int lane_c = chunk & 63;
        const int rest = chunk >> 6;         // t*S + s
        const int s = rest % S;
        const int t = rest / S;
        const int c = (ch * TW + t) * 16 + (lane_c & 15);
        const int k0 = s * 32 + (lane_c >> 4) * 8;
        short8 pack;
#pragma unroll
        for (int j = 0; j < 8; ++j) {
            float w = 0.f;
            const int k = k0 + j;
            if (c < DP) w = Wl[k * DP + c];
            else if (c < DP + DR) w = Wr[k * DR + (c - DP)];
            pack[j] = (short)f2b(w);
        }
        *reinterpret_cast<short8*>(&sF[(size_t)chunk * 8]) = pack;
    }
    __syncthreads();

    const int wave = tid >> 6, lane = tid & 63;
    const int ng = wave;                 // all waves in block share ch
    const int q = lane >> 4, ln = lane & 15;
    const int colbase = ch * (TW * 16);

    // lane's fragment base: frag (t,s) at +(t*S+s)*512 ushorts
    const unsigned short* fbase = &sF[(size_t)lane * 8];

    int colg[TW];
    float bias[TW];
#pragma unroll
    for (int t = 0; t < TW; ++t) {
        colg[t] = colbase + t * 16 + ln;
        bias[t] = (colg[t] >= DP && colg[t] < DP + DR) ? bl[colg[t] - DP] : 0.0f;
    }

    // raw-x double buffers (unused dtype pair is DCE'd)
    float4 rf0[NU][2 * S], rf1[NU][2 * S];
    short8 rb0[NU][S], rb1[NU][S];

    auto load_groups = [&](float4 (&rf)[NU][2 * S], short8 (&rb)[NU][S], int nbase) {
#pragma unroll
        for (int g = 0; g < NU; ++g) {
            const int base = nbase + (ng * NU + g) * 16;
            if (base >= n) continue;  // wave-uniform
            if constexpr (IN_BF16) {
                const unsigned short* xr =
                    (const unsigned short*)xv + (size_t)(base + ln) * DIN + q * 8;
#pragma unroll
                for (int s = 0; s < S; ++s)
                    rb[g][s] = *reinterpret_cast<const short8*>(xr + s * 32);
            } else {
                const float* xr = (const float*)xv + (size_t)(base + ln) * DIN + q * 8;
#pragma unroll
                for (int s = 0; s < S; ++s) {
                    rf[g][2 * s]     = *reinterpret_cast<const float4*>(xr + s * 32);
                    rf[g][2 * s + 1] = *reinterpret_cast<const float4*>(xr + s * 32 + 4);
                }
            }
        }
    };

    auto compute_groups = [&](float4 (&rf)[NU][2 * S], short8 (&rb)[NU][S], int nbase) {
#pragma unroll
        for (int g = 0; g < NU; ++g) {
            const int base = nbase + (ng * NU + g) * 16;
            if (base >= n) continue;
            short8 af[S];
#pragma unroll
            for (int s = 0; s < S; ++s) {
                if constexpr (IN_BF16) {
                    short8 a = rb[g][s];
                    if (RELU) {
#pragma unroll
                        for (int j = 0; j < 8; ++j)
                            a[j] = ((short)a[j] < 0) ? (short)0 : a[j];
                    }
                    af[s] = a;
                } else {
                    float4 v0 = rf[g][2 * s], v1 = rf[g][2 * s + 1];
                    if (RELU) {
                        v0.x = fmaxf(v0.x, 0.0f); v0.y = fmaxf(v0.y, 0.0f);
                        v0.z = fmaxf(v0.z, 0.0f); v0.w = fmaxf(v0.w, 0.0f);
                        v1.x = fmaxf(v1.x, 0.0f); v1.y = fmaxf(v1.y, 0.0f);
                        v1.z = fmaxf(v1.z, 0.0f); v1.w = fmaxf(v1.w, 0.0f);
                    }
                    short8 a;
                    a[0] = (short)f2b(v0.x); a[1] = (short)f2b(v0.y);
                    a[2] = (short)f2b(v0.z); a[3] = (short)f2b(v0.w);
                    a[4] = (short)f2b(v1.x); a[5] = (short)f2b(v1.y);
                    a[6] = (short)f2b(v1.z); a[7] = (short)f2b(v1.w);
                    af[s] = a;
                }
            }

            f32x4 acc[TW];
#pragma unroll
            for (int t = 0; t < TW; ++t) acc[t] = (f32x4){0.f, 0.f, 0.f, 0.f};
#pragma unroll
            for (int s = 0; s < S; ++s)
#pragma unroll
                for (int t = 0; t < TW; ++t) {
                    short8 bf = *reinterpret_cast<const short8*>(
                        fbase + (size_t)(t * S + s) * 512);
                    acc[t] = __builtin_amdgcn_mfma_f32_16x16x32_bf16(
                        af[s], bf, acc[t], 0, 0, 0);
                }

#pragma unroll
            for (int t = 0; t < TW; ++t) {
                const int c = colg[t];
#pragma unroll
                for (int rr = 0; rr < 4; ++rr) {
                    const int row = base + q * 4 + rr;
                    if (c < DP) {
                        if constexpr (OUT_BF16)
                            ((unsigned short*)pv)[(size_t)row * DP + c] = f2b(acc[t][rr]);
                        else
                            ((float*)pv)[(size_t)row * DP + c] = acc[t][rr];
                    } else if (c < DP + DR) {
                        const float v = acc[t][rr] + bias[t];
                        if constexpr (OUT_BF16)
                            ((unsigned short*)rv)[(size_t)row * DR + (c - DP)] = f2b(v);
                        else
                            ((float*)rv)[(size_t)row * DR + (c - DP)] = v;
                    }
                }
            }
        }
    };

    const int npi = WAVES * NU * 16;     // nodes per block-iteration
    const int stride = nblk * npi;
    int nb = blk * npi;
    if (nb >= n) return;
    load_groups(rf0, rb0, nb);
    while (true) {
        const int nb1 = nb + stride;
        if (nb1 < n) load_groups(rf1, rb1, nb1);
        compute_groups(rf0, rb0, nb);
        nb = nb1;
        if (nb >= n) break;
        const int nb2 = nb + stride;
        if (nb2 < n) load_groups(rf0, rb0, nb2);
        compute_groups(rf1, rb1, nb);
        nb = nb2;
        if (nb >= n) break;
    }
}

// ============================ aggregation ==================================
// out[d] += mean over csr row of p rows. bf16 buffers: L=D/8 lanes per node,
// one short8 per lane per gathered row; fp32 accumulation; unroll-4 keeps
// 4 independent csr->row chains in flight.

template <int D, int L>
__global__ void agg_bf16(const int* __restrict__ rowptr,
                         const int* __restrict__ csr,
                         const unsigned short* __restrict__ p,
                         unsigned short* __restrict__ out,
                         int n) {
    constexpr int RQ = D / 8;            // short8s per row
    long long gid = (long long)blockIdx.x * blockDim.x + threadIdx.x;
    int d = (int)(gid / L);
    int l = (int)(gid % L);
    if (d >= n) return;
    int beg = rowptr[d], end = rowptr[d + 1];
    int deg = end - beg;
    if (deg <= 0) return;

    const short8* pr = reinterpret_cast<const short8*>(p);
    float s[8];
#pragma unroll
    for (int j = 0; j < 8; ++j) s[j] = 0.0f;

    int i = beg;
    for (; i + 4 <= end; i += 4) {
        int e0 = csr[i], e1 = csr[i + 1], e2 = csr[i + 2], e3 = csr[i + 3];
        short8 a = pr[(size_t)e0 * RQ + l];
        short8 b = pr[(size_t)e1 * RQ + l];
        short8 c = pr[(size_t)e2 * RQ + l];
        short8 e = pr[(size_t)e3 * RQ + l];
#pragma unroll
        for (int j = 0; j < 8; ++j)
            s[j] += (b2f((unsigned short)a[j]) + b2f((unsigned short)b[j])) +
                    (b2f((unsigned short)c[j]) + b2f((unsigned short)e[j]));
    }
    for (; i < end; ++i) {
        short8 a = pr[(size_t)csr[i] * RQ + l];
#pragma unroll
        for (int j = 0; j < 8; ++j) s[j] += b2f((unsigned short)a[j]);
    }

    const float inv = 1.0f / (float)deg;
    short8* o = reinterpret_cast<short8*>(out) + (size_t)d * RQ + l;
    short8 cur = *o;
#pragma unroll
    for (int j = 0; j < 8; ++j) {
        float v = b2f((unsigned short)cur[j]) + s[j] * inv;
        cur[j] = (short)f2b(v);
    }
    *o = cur;
}

// fp32 variant for the final layer (out = d_out, fp32)
template <int D, int L>
__global__ void agg_f32(const int* __restrict__ rowptr,
                        const int* __restrict__ csr,
                        const float* __restrict__ p,
                        float* __restrict__ out,
                        int n) {
    constexpr int RQ = D / 4;            // float4s per row
    long long gid = (long long)blockIdx.x * blockDim.x + threadIdx.x;
    int d = (int)(gid / L);
    int l = (int)(gid % L);
    if (d >= n || l >= RQ) return;
    int beg = rowptr[d], end = rowptr[d + 1];
    int deg = end - beg;
    if (deg <= 0) return;

    const float4* pr = reinterpret_cast<const float4*>(p);
    float sx = 0.f, sy = 0.f, sz = 0.f, sw = 0.f;
    int i = beg;
    for (; i + 4 <= end; i += 4) {
        int s0 = csr[i], s1 = csr[i + 1], s2 = csr[i + 2], s3 = csr[i + 3];
        float4 a = pr[(size_t)s0 * RQ + l];
        float4 b = pr[(size_t)s1 * RQ + l];
        float4 c = pr[(size_t)s2 * RQ + l];
        float4 e = pr[(size_t)s3 * RQ + l];
        sx += (a.x + b.x) + (c.x + e.x);
        sy += (a.y + b.y) + (c.y + e.y);
        sz += (a.z + b.z) + (c.z + e.z);
        sw += (a.w + b.w) + (c.w + e.w);
    }
    for (; i < end; ++i) {
        float4 a = pr[(size_t)csr[i] * RQ + l];
        sx += a.x; sy += a.y; sz += a.z; sw += a.w;
    }
    const float inv = 1.0f / (float)deg;
    float4* o = reinterpret_cast<float4*>(out) + (size_t)d * RQ + l;
    float4 cur = *o;
    cur.x += sx * inv; cur.y += sy * inv;
    cur.z += sz * inv; cur.w += sw * inv;
    *o = cur;
}

// ============================ launcher =====================================

extern "C" void kernel_launch(void* const* d_in, const int* in_sizes, int n_in,
                              void* d_out, int out_size, void* d_ws, size_t ws_size,
                              hipStream_t stream) {
    const float* x   = (const float*)d_in[0];
    const int*   ei  = (const int*)d_in[1];   // (2, E) int32
    const float* Wl1 = (const float*)d_in[2];
    const float* bl1 = (const float*)d_in[3];
    const float* Wr1 = (const float*)d_in[4];
    const float* Wl2 = (const float*)d_in[5];
    const float* bl2 = (const float*)d_in[6];
    const float* Wr2 = (const float*)d_in[7];
    const float* Wl3 = (const float*)d_in[8];
    const float* bl3 = (const float*)d_in[9];
    const float* Wr3 = (const float*)d_in[10];
    float* out = (float*)d_out;

    const int N = in_sizes[0] / 128;
    const int E = in_sizes[1] / 2;
    const int* src  = ei;
    const int* dstp = ei + E;

    // workspace (bf16 intermediates):
    //   A1 bf16 N*64 | B bf16 N*64 | A2 bf16 N*32 | C bf16 N*32 |
    //   A3 f32 N*20 | rowptr (N+1) | csr (E)
    // transient CSR ints (degi, cursor, bsum) alias A3 (dead before proj3).
    unsigned short* A1 = (unsigned short*)d_ws;
    unsigned short* Bb = A1 + (size_t)N * 64;
    unsigned short* A2 = Bb + (size_t)N * 64;
    unsigned short* Cb = A2 + (size_t)N * 32;
    float* A3 = (float*)(Cb + (size_t)N * 32);
    int* rowptr = (int*)(A3 + (size_t)N * 20);
    int* csr    = rowptr + (N + 1);

    int* degi   = (int*)A3;
    int* cursor = degi + N;
    int* bsum   = cursor + N;

    const int NB = (N + 255) / 256;  // 782 <= 1024 (scan_top limit)

    // --- CSR build ---
    zero_ints<<<NB, 256, 0, stream>>>(degi, N);
    hist_kernel<<<(E + 255) / 256, 256, 0, stream>>>(dstp, degi, E);
    scan_reduce<<<NB, 256, 0, stream>>>(degi, bsum, N);
    scan_top<<<1, 1024, 0, stream>>>(bsum, NB);
    scan_final<<<NB, 256, 0, stream>>>(degi, bsum, rowptr, cursor, N, E);
    fill_kernel<<<(E + 255) / 256, 256, 0, stream>>>(src, dstp, cursor, csr, E);

    // --- layer 1: 128 -> 64 --- fp32 in, bf16 out; block-ch CH=2
    // LDS 16 KB, VGPR 64 -> 8 blocks/CU = 32 waves/CU. npi=64/block,
    // grid 2048 = 1024 node-blocks x 2 ch classes (~3 iters/block).
    proj_mfma<128, 64, 64, 128, 2, 1, false, false, true><<<2048, 256, 0, stream>>>(
        x, Wl1, Wr1, bl1, A1, Bb, N);
    agg_bf16<64, 8><<<(int)(((long long)N * 8 + 255) / 256), 256, 0, stream>>>(
        rowptr, csr, A1, Bb, N);

    // --- layer 2: 64 -> 32 --- bf16 in (relu), bf16 out; CH=1, NU=2
    // npi=128, grid 1563 (one trip); rb buffers 32 regs -> target VGPR<=64
    proj_mfma<64, 32, 32, 64, 1, 2, true, true, true><<<1563, 256, 0, stream>>>(
        Bb, Wl2, Wr2, bl2, A2, Cb, N);
    agg_bf16<32, 4><<<(int)(((long long)N * 4 + 255) / 256), 256, 0, stream>>>(
        rowptr, csr, A2, Cb, N);

    // --- layer 3: 32 -> 20 --- bf16 in (relu), fp32 out (p3=A3, r -> d_out)
    proj_mfma<32, 20, 20, 48, 1, 2, true, true, false><<<1563, 256, 0, stream>>>(
        Cb, Wl3, Wr3, bl3, A3, out, N);
    agg_f32<20, 8><<<(int)(((long long)N * 8 + 255) / 256), 256, 0, stream>>>(
        rowptr, csr, A3, out, N);
}